// Round 4
// baseline (329.188 us; speedup 1.0000x reference)
//
#include <hip/hip_runtime.h>
#include <hip/hip_bf16.h>
#include <math.h>

// Problem constants (fixed by reference)
#define NN 100000   // nodes
#define FF 128      // features
#define DD 16       // degree
#define KK 8        // hashers
#define HH 256      // hash dim
#define OO 256      // out dim
#define KH 2048     // K*H
// C[NN,256] = A[NN,256](bf16) @ Bw[256,256](bf16), K = 2F = 256.
// A cols 0..127 = mean(neigh), 128..255 = self. Bw rows: 0..127 Wn-part, 128..255 Ws-part.
// R4: TWO launches total.
//   k_prep: blocks 0-1 = weight GEMM via bf16 MFMA (Bbf[o][f2] = sum_j R2[f][j]*W[o][j],
//           inline fp32->bf16 cast in staging; replaces k_wgemm+k_comb+P roundtrip);
//           blocks 2.. = x fp32->bf16 cast (overlaps the 2 weight blocks).
//   k_fused: gather MLP doubled (16 loads in flight/group), K-loop unroll 2,
//           __expf-based ELU. Full-line epilogue kept (R3: WRITE hit exact ideal).

using frag_t  = __attribute__((ext_vector_type(8))) short;   // 8 bf16 = 4 VGPR (MFMA A/B frag)
using f32x4   = __attribute__((ext_vector_type(4))) float;   // MFMA C/D frag
using ushort8 = __attribute__((ext_vector_type(8))) unsigned short;

static __device__ __forceinline__ float blo(unsigned int u) {   // low bf16 of packed pair
    union { unsigned int i; float f; } v; v.i = u << 16; return v.f;
}
static __device__ __forceinline__ float bhi(unsigned int u) {   // high bf16 of packed pair
    union { unsigned int i; float f; } v; v.i = u & 0xffff0000u; return v.f;
}
static __device__ __forceinline__ unsigned short f2bf(float f) {
    union { float f; unsigned int i; } v; v.f = f;
    unsigned int x = v.i;
    x += 0x7fffu + ((x >> 16) & 1u);   // round-to-nearest-even
    return (unsigned short)(x >> 16);
}
static __device__ __forceinline__ unsigned int pk2(float a, float b) {
    return (unsigned int)f2bf(a) | ((unsigned int)f2bf(b) << 16);
}

// ---------------- Kernel 1: prep = weight-MFMA (blocks 0,1) + x cast (blocks 2..) ----------------
// Weight blocks: C[o=256][f=128] = Wsel[o][j] * R2[f][j], K=2048, 8 waves as 4(M)x2(N),
//   wave tile 64x64 (acc 4x4 frags of 16x16x32). Staging casts fp32->bf16 inline.
//   R2[f][j] = R[j>>8][f][j&255]; kt-tile of 64 j's lies inside one hash chunk.
// Cast blocks: 512 thr x 8 floats; 3125 blocks cover 12.8M elements exactly.
__global__ __launch_bounds__(512) void k_prep(const float* __restrict__ x,
                                              const float* __restrict__ R,
                                              const float* __restrict__ Ws,
                                              const float* __restrict__ Wn,
                                              unsigned short* __restrict__ xb,
                                              unsigned short* __restrict__ Bbf) {
    __shared__ __align__(16) unsigned short Aw[256][72];   // W tile, bf16 (36.9 KB)
    __shared__ __align__(16) unsigned short Bw[128][72];   // R tile, bf16 (18.4 KB)
    int b = blockIdx.x;
    int t = threadIdx.x;
    if (b >= 2) {
        // ---- cast path ----
        int g = (b - 2) * 512 + t;
        const float4* xv = (const float4*)x;
        float4 a = xv[2 * g], c = xv[2 * g + 1];
        ushort8 o;
        o[0] = f2bf(a.x); o[1] = f2bf(a.y); o[2] = f2bf(a.z); o[3] = f2bf(a.w);
        o[4] = f2bf(c.x); o[5] = f2bf(c.y); o[6] = f2bf(c.z); o[7] = f2bf(c.w);
        *(ushort8*)(xb + (size_t)g * 8) = o;
        return;
    }
    // ---- weight MFMA path: b=0 -> Wn (f2 0..127), b=1 -> Ws (f2 128..255) ----
    const float* W = (b == 0) ? Wn : Ws;
    int lane = t & 63, wv = t >> 6;
    int wm = wv >> 1, wn = wv & 1;            // 4x2 waves, 64x64 each
    int l15 = lane & 15, quad = lane >> 4;
    f32x4 acc[4][4] = {};
    for (int kt = 0; kt < 32; ++kt) {         // BK = 64
        __syncthreads();                       // prev iteration's frag reads done
#pragma unroll
        for (int s = 0; s < 8; ++s) {         // A: 256 rows x 16 float4-chunks
            int c = s * 512 + t;
            int row = c >> 4, c4 = c & 15;
            float4 v = *(const float4*)(W + (size_t)row * KH + kt * 64 + c4 * 4);
            uint2 p; p.x = pk2(v.x, v.y); p.y = pk2(v.z, v.w);
            *(uint2*)&Aw[row][c4 * 4] = p;
        }
#pragma unroll
        for (int s = 0; s < 4; ++s) {         // B: 128 rows x 16 chunks from R
            int c = s * 512 + t;
            int row = c >> 4, c4 = c & 15;
            float4 v = *(const float4*)(R + (size_t)(kt >> 2) * 32768
                                          + (size_t)row * 256 + (kt & 3) * 64 + c4 * 4);
            uint2 p; p.x = pk2(v.x, v.y); p.y = pk2(v.z, v.w);
            *(uint2*)&Bw[row][c4 * 4] = p;
        }
        __syncthreads();
#pragma unroll
        for (int k2 = 0; k2 < 2; ++k2) {
            frag_t af[4], bfr[4];
#pragma unroll
            for (int i = 0; i < 4; ++i)
                af[i] = *(const frag_t*)&Aw[wm * 64 + i * 16 + l15][k2 * 32 + quad * 8];
#pragma unroll
            for (int j = 0; j < 4; ++j)
                bfr[j] = *(const frag_t*)&Bw[wn * 64 + j * 16 + l15][k2 * 32 + quad * 8];
#pragma unroll
            for (int i = 0; i < 4; ++i)
#pragma unroll
                for (int j = 0; j < 4; ++j)
                    acc[i][j] = __builtin_amdgcn_mfma_f32_16x16x32_bf16(af[i], bfr[j], acc[i][j], 0, 0, 0);
        }
    }
    // write Bbf[o][b*128 + f]; C/D layout: col(n)=l15-based, row(m)=quad*4+reg (m89-verified)
#pragma unroll
    for (int j = 0; j < 4; ++j) {
        int f = wn * 64 + j * 16 + l15;
#pragma unroll
        for (int i = 0; i < 4; ++i) {
            int o0 = wm * 64 + i * 16 + quad * 4;
#pragma unroll
            for (int r = 0; r < 4; ++r)
                Bbf[(size_t)(o0 + r) * 256 + b * 128 + f] = f2bf(acc[i][j][r]);
        }
    }
}

// --------- Kernel 2 (fused): gather-mean -> LDS A-tile -> MFMA GEMM + bias + ELU ---------
// BM=64 x BN=256, 512 threads = 8 waves, wave tile 64x32 (acc 4x2 frags).
// Gather: lane=(r4,l16) -> one dwordx4 gathers 4 rows x 16B; ALL 16 nbr loads issued
//   per group (compiler's progressive vmcnt overlaps unpack with loads in flight).
// LDS: Als[64][264] bf16 only (33.8 KB); B-frags straight from global (128 KB, L2-hot);
//   K-loop barrier-free, unroll 2 so B loads pipeline across kt.
// Epilogue: acc -> LDS float[32][260] (reuse Als) -> full-line float4 stores, 2 passes.
__global__ __launch_bounds__(512, 4) void k_fused(const unsigned short* __restrict__ xb,
                                                  const int* __restrict__ nbr,
                                                  const unsigned short* __restrict__ Bw,
                                                  const float* __restrict__ bias,
                                                  float* __restrict__ C) {
    __shared__ __align__(16) char smraw[64 * 264 * 2];   // 33792 B, dual-purpose
    unsigned short (*Als)[264] = (unsigned short (*)[264])smraw;
    float* Fls = (float*)smraw;                          // [32][260] floats (33280 B)
    const int FLS_W = 260;

    int m0 = blockIdx.x * 64;
    int t = threadIdx.x;
    int lane = t & 63, wv = t >> 6;           // 8 waves
    int l15 = lane & 15, quad = lane >> 4;
    int l16 = lane & 15, r4 = lane >> 4;      // gather mapping: 4 rows x 16 feature-lanes
    int selbase = (lane & 48) << 2;           // bpermute selector base (group start lane *4)

    // ---- gather phase: 2 groups of 4 rows; 16 dwordx4 gathers in flight per group
#pragma unroll
    for (int g = 0; g < 2; ++g) {
        int row = wv * 8 + g * 4 + r4;                    // block-local row 0..63
        int node = m0 + row; if (node >= NN) node = NN - 1;
        int myidx = nbr[(size_t)node * 16 + l16];         // lane holds nbr #l16 of its row
        uint4 selfv = *(const uint4*)(xb + (size_t)node * 128 + l16 * 8);
        uint4 gv[16];
#pragma unroll
        for (int d = 0; d < 16; ++d) {
            int bi = __builtin_amdgcn_ds_bpermute(selbase + (d << 2), myidx);
            gv[d] = *(const uint4*)(xb + (size_t)bi * 128 + l16 * 8);
        }
        float s[8] = {0.f, 0.f, 0.f, 0.f, 0.f, 0.f, 0.f, 0.f};
#pragma unroll
        for (int d = 0; d < 16; ++d) {
            s[0] += blo(gv[d].x); s[1] += bhi(gv[d].x);
            s[2] += blo(gv[d].y); s[3] += bhi(gv[d].y);
            s[4] += blo(gv[d].z); s[5] += bhi(gv[d].z);
            s[6] += blo(gv[d].w); s[7] += bhi(gv[d].w);
        }
        ushort8 o;
#pragma unroll
        for (int k = 0; k < 8; ++k) o[k] = f2bf(s[k] * 0.0625f);
        *(ushort8*)&Als[row][l16 * 8] = o;                // mean features 0..127
        *(uint4*)&Als[row][128 + l16 * 8] = selfv;        // self features 128..255
    }
    __syncthreads();

    // ---- K-loop: barrier-free; B-frags from global (L2-hot 128 KB)
    f32x4 acc[4][2] = {};
#pragma unroll 2
    for (int kt = 0; kt < 4; ++kt) {
#pragma unroll
        for (int k2 = 0; k2 < 2; ++k2) {
            frag_t bfr[2], af[4];
#pragma unroll
            for (int j = 0; j < 2; ++j)
                bfr[j] = *(const frag_t*)(Bw + (size_t)(wv * 32 + j * 16 + l15) * 256
                                             + kt * 64 + k2 * 32 + quad * 8);
#pragma unroll
            for (int i = 0; i < 4; ++i)
                af[i] = *(const frag_t*)&Als[i * 16 + l15][kt * 64 + k2 * 32 + quad * 8];
#pragma unroll
            for (int i = 0; i < 4; ++i)
#pragma unroll
                for (int j = 0; j < 2; ++j)
                    acc[i][j] = __builtin_amdgcn_mfma_f32_16x16x32_bf16(af[i], bfr[j], acc[i][j], 0, 0, 0);
        }
    }

    // ---- epilogue: bias+ELU in-reg, stage 32-row halves in LDS, full-line float4 stores
    float bv[2];
#pragma unroll
    for (int j = 0; j < 2; ++j) bv[j] = bias[wv * 32 + j * 16 + l15];
#pragma unroll
    for (int p = 0; p < 2; ++p) {
        __syncthreads();     // p=0: Als frag reads done; p=1: prev pass reads done
#pragma unroll
        for (int ii = 0; ii < 2; ++ii) {
            int i = p * 2 + ii;
#pragma unroll
            for (int j = 0; j < 2; ++j) {
                int col = wv * 32 + j * 16 + l15;
#pragma unroll
                for (int r = 0; r < 4; ++r) {
                    int lr = ii * 16 + quad * 4 + r;      // local row within 32-row pass
                    float v = acc[i][j][r] + bv[j];
                    v = (v > 0.f) ? v : (__expf(v) - 1.0f);   // ELU(alpha=1), fast exp
                    Fls[lr * FLS_W + col] = v;
                }
            }
        }
        __syncthreads();
#pragma unroll
        for (int q = 0; q < 4; ++q) {                     // 32 rows x 256 cols, float4
            int f4 = q * 512 + t;
            int lr = f4 >> 6, c4 = f4 & 63;
            int grow = m0 + p * 32 + lr;
            if (grow < NN)
                *(float4*)(C + (size_t)grow * 256 + c4 * 4) = *(const float4*)&Fls[lr * FLS_W + c4 * 4];
        }
    }
}

// ---------------------------------- launcher ----------------------------------
extern "C" void kernel_launch(void* const* d_in, const int* in_sizes, int n_in,
                              void* d_out, int out_size, void* d_ws, size_t ws_size,
                              hipStream_t stream) {
    const float* x    = (const float*)d_in[0];
    const int*   nbr  = (const int*)d_in[1];
    const float* R    = (const float*)d_in[2];
    const float* Ws   = (const float*)d_in[3];
    const float* Wn   = (const float*)d_in[4];
    const float* bias = (const float*)d_in[5];
    float* out = (float*)d_out;

    // workspace layout (all 16B-aligned): ~25.7 MB (P intermediate eliminated)
    char* ws = (char*)d_ws;
    unsigned short* xb  = (unsigned short*)(ws);              // 25,600,000 B
    unsigned short* Bbf = (unsigned short*)(ws + 25600000);   //    131,072 B

    // 3127 blocks: 0,1 = weight MFMA GEMM; 2..3126 = x cast (3125 * 512 * 8 = 12.8M elems)
    hipLaunchKernelGGL(k_prep,  dim3(3127), dim3(512), 0, stream, x, R, Ws, Wn, xb, Bbf);
    hipLaunchKernelGGL(k_fused, dim3(1563), dim3(512), 0, stream, xb, nbr, Bbf, bias, out);
}

// Round 5
// 269.682 us; speedup vs baseline: 1.2207x; 1.2207x over previous
//
#include <hip/hip_runtime.h>
#include <hip/hip_bf16.h>
#include <math.h>

// Problem constants (fixed by reference)
#define NN 100000   // nodes
#define FF 128      // features
#define DD 16       // degree
#define KK 8        // hashers
#define HH 256      // hash dim
#define OO 256      // out dim
#define KH 2048     // K*H
// C[NN,256] = A[NN,256](bf16) @ Bw[256,256](bf16), K = 2F = 256.
// A cols 0..127 = mean(neigh), 128..255 = self. Bw rows: 0..127 Wn-part, 128..255 Ws-part.
// R5: k_prep weight path parallelized 2 -> 8 blocks (R4 post-mortem: 2 blocks ran a serial
//     K=2048 loop on 2 CUs = 131 us at 3% occupancy). 8 blocks of 64(o)x128(f), K=2048,
//     hidden under 3125 cast blocks. k_fused reverted to the R3-proven version (101 us,
//     VGPR 60) + __expf ELU only.

using frag_t  = __attribute__((ext_vector_type(8))) short;   // 8 bf16 = 4 VGPR (MFMA A/B frag)
using f32x4   = __attribute__((ext_vector_type(4))) float;   // MFMA C/D frag
using ushort8 = __attribute__((ext_vector_type(8))) unsigned short;

static __device__ __forceinline__ float blo(unsigned int u) {   // low bf16 of packed pair
    union { unsigned int i; float f; } v; v.i = u << 16; return v.f;
}
static __device__ __forceinline__ float bhi(unsigned int u) {   // high bf16 of packed pair
    union { unsigned int i; float f; } v; v.i = u & 0xffff0000u; return v.f;
}
static __device__ __forceinline__ unsigned short f2bf(float f) {
    union { float f; unsigned int i; } v; v.f = f;
    unsigned int x = v.i;
    x += 0x7fffu + ((x >> 16) & 1u);   // round-to-nearest-even
    return (unsigned short)(x >> 16);
}
static __device__ __forceinline__ unsigned int pk2(float a, float b) {
    return (unsigned int)f2bf(a) | ((unsigned int)f2bf(b) << 16);
}

// ------- Kernel 1: prep = weight-MFMA (blocks 0..7) + x cast (blocks 8..3132) -------
// Weight block b (0..7): w=b>>2 (0=Wn,1=Ws), ot=b&3. Output Bbf[o][w*128+f] for
//   o in [ot*64,+64), f in [0,128): sum_j R[j>>8][f][j&255] * W[o][j], K=2048.
//   8 waves as 2(o)x4(f), wave tile 32x32, acc 2x2 frags 16x16x32. BK=64, 32 kt iters,
//   inline fp32->bf16 cast during LDS staging.
// Cast blocks: 512 thr x 8 floats; 3125 blocks cover 12.8M elements exactly.
__global__ __launch_bounds__(512) void k_prep(const float* __restrict__ x,
                                              const float* __restrict__ R,
                                              const float* __restrict__ Ws,
                                              const float* __restrict__ Wn,
                                              unsigned short* __restrict__ xb,
                                              unsigned short* __restrict__ Bbf) {
    __shared__ __align__(16) unsigned short Aw[64][72];    // W tile, bf16 ( 9.2 KB)
    __shared__ __align__(16) unsigned short Bw[128][72];   // R tile, bf16 (18.4 KB)
    int b = blockIdx.x;
    int t = threadIdx.x;
    if (b >= 8) {
        // ---- cast path ----
        int g = (b - 8) * 512 + t;
        const float4* xv = (const float4*)x;
        float4 a = xv[2 * g], c = xv[2 * g + 1];
        ushort8 o;
        o[0] = f2bf(a.x); o[1] = f2bf(a.y); o[2] = f2bf(a.z); o[3] = f2bf(a.w);
        o[4] = f2bf(c.x); o[5] = f2bf(c.y); o[6] = f2bf(c.z); o[7] = f2bf(c.w);
        *(ushort8*)(xb + (size_t)g * 8) = o;
        return;
    }
    // ---- weight MFMA path ----
    const int w = b >> 2, ot = b & 3;
    const float* W = (w == 0) ? Wn : Ws;
    int lane = t & 63, wv = t >> 6;
    int wo = wv >> 2, wf = wv & 3;            // 2(o) x 4(f) waves, 32x32 each
    int l15 = lane & 15, quad = lane >> 4;
    f32x4 acc[2][2] = {};
    for (int kt = 0; kt < 32; ++kt) {         // BK = 64
        __syncthreads();                      // prev iteration's frag reads done
#pragma unroll
        for (int s = 0; s < 2; ++s) {         // A: 64 rows x 16 float4-chunks of W
            int c = s * 512 + t;
            int row = c >> 4, c4 = c & 15;
            float4 v = *(const float4*)(W + (size_t)(ot * 64 + row) * KH + kt * 64 + c4 * 4);
            uint2 p; p.x = pk2(v.x, v.y); p.y = pk2(v.z, v.w);
            *(uint2*)&Aw[row][c4 * 4] = p;
        }
#pragma unroll
        for (int s = 0; s < 4; ++s) {         // B: 128 rows x 16 chunks of R2
            int c = s * 512 + t;
            int row = c >> 4, c4 = c & 15;
            float4 v = *(const float4*)(R + (size_t)(kt >> 2) * 32768
                                          + (size_t)row * 256 + (kt & 3) * 64 + c4 * 4);
            uint2 p; p.x = pk2(v.x, v.y); p.y = pk2(v.z, v.w);
            *(uint2*)&Bw[row][c4 * 4] = p;
        }
        __syncthreads();
#pragma unroll
        for (int k2 = 0; k2 < 2; ++k2) {
            frag_t af[2], bfr[2];
#pragma unroll
            for (int i = 0; i < 2; ++i)
                af[i] = *(const frag_t*)&Aw[wo * 32 + i * 16 + l15][k2 * 32 + quad * 8];
#pragma unroll
            for (int j = 0; j < 2; ++j)
                bfr[j] = *(const frag_t*)&Bw[wf * 32 + j * 16 + l15][k2 * 32 + quad * 8];
#pragma unroll
            for (int i = 0; i < 2; ++i)
#pragma unroll
                for (int j = 0; j < 2; ++j)
                    acc[i][j] = __builtin_amdgcn_mfma_f32_16x16x32_bf16(af[i], bfr[j], acc[i][j], 0, 0, 0);
        }
    }
    // write Bbf[o][w*128+f]; C/D layout: col(n)=l15 -> f (R-row), row(m)=quad*4+r -> o (W-row)
#pragma unroll
    for (int j = 0; j < 2; ++j) {
        int f = wf * 32 + j * 16 + l15;
#pragma unroll
        for (int i = 0; i < 2; ++i) {
            int o0 = ot * 64 + wo * 32 + i * 16 + quad * 4;
#pragma unroll
            for (int r = 0; r < 4; ++r)
                Bbf[(size_t)(o0 + r) * 256 + w * 128 + f] = f2bf(acc[i][j][r]);
        }
    }
}

// --------- Kernel 2 (fused): gather-mean -> LDS A-tile -> MFMA GEMM + bias + ELU ---------
// BM=64 x BN=256, 512 threads = 8 waves, wave tile 64x32 (acc 4x2 frags). (R3-proven)
// Gather: lane=(r4,l16) -> one dwordx4 gathers 4 rows x 16B; nbr idx broadcast per-d
//   via ds_bpermute; 2 batches of 8 loads in flight (VGPR 60, no spills).
// LDS: Als[64][264] bf16 only (33.8 KB); B-frags straight from global (128 KB, L2-hot);
//   K-loop barrier-free.
// Epilogue: acc -> LDS float[32][260] (reuse Als) -> full-line float4 stores, 2 passes.
__global__ __launch_bounds__(512, 4) void k_fused(const unsigned short* __restrict__ xb,
                                                  const int* __restrict__ nbr,
                                                  const unsigned short* __restrict__ Bw,
                                                  const float* __restrict__ bias,
                                                  float* __restrict__ C) {
    __shared__ __align__(16) char smraw[64 * 264 * 2];   // 33792 B, dual-purpose
    unsigned short (*Als)[264] = (unsigned short (*)[264])smraw;
    float* Fls = (float*)smraw;                          // [32][260] floats (33280 B)
    const int FLS_W = 260;

    int m0 = blockIdx.x * 64;
    int t = threadIdx.x;
    int lane = t & 63, wv = t >> 6;           // 8 waves
    int l15 = lane & 15, quad = lane >> 4;
    int l16 = lane & 15, r4 = lane >> 4;      // gather mapping: 4 rows x 16 feature-lanes
    int selbase = (lane & 48) << 2;           // bpermute selector base (group start lane *4)

    // ---- gather phase: 2 groups of 4 rows; per group 2 batches of 8 dwordx4 in flight
#pragma unroll
    for (int g = 0; g < 2; ++g) {
        int row = wv * 8 + g * 4 + r4;                    // block-local row 0..63
        int node = m0 + row; if (node >= NN) node = NN - 1;
        int myidx = nbr[(size_t)node * 16 + l16];         // lane holds nbr #l16 of its row
        uint4 selfv = *(const uint4*)(xb + (size_t)node * 128 + l16 * 8);
        float s[8] = {0.f, 0.f, 0.f, 0.f, 0.f, 0.f, 0.f, 0.f};
#pragma unroll
        for (int h = 0; h < 2; ++h) {                     // 2 batches of 8 loads in flight
            uint4 gv[8];
#pragma unroll
            for (int d = 0; d < 8; ++d) {
                int bi = __builtin_amdgcn_ds_bpermute(selbase + ((h * 8 + d) << 2), myidx);
                gv[d] = *(const uint4*)(xb + (size_t)bi * 128 + l16 * 8);
            }
#pragma unroll
            for (int d = 0; d < 8; ++d) {
                s[0] += blo(gv[d].x); s[1] += bhi(gv[d].x);
                s[2] += blo(gv[d].y); s[3] += bhi(gv[d].y);
                s[4] += blo(gv[d].z); s[5] += bhi(gv[d].z);
                s[6] += blo(gv[d].w); s[7] += bhi(gv[d].w);
            }
        }
        ushort8 o;
#pragma unroll
        for (int k = 0; k < 8; ++k) o[k] = f2bf(s[k] * 0.0625f);
        *(ushort8*)&Als[row][l16 * 8] = o;                // mean features 0..127
        *(uint4*)&Als[row][128 + l16 * 8] = selfv;        // self features 128..255
    }
    __syncthreads();

    // ---- K-loop: barrier-free; B-frags from global (L2-hot 128 KB)
    f32x4 acc[4][2] = {};
#pragma unroll 1
    for (int kt = 0; kt < 4; ++kt) {
#pragma unroll
        for (int k2 = 0; k2 < 2; ++k2) {
            frag_t bfr[2], af[4];
#pragma unroll
            for (int j = 0; j < 2; ++j)
                bfr[j] = *(const frag_t*)(Bw + (size_t)(wv * 32 + j * 16 + l15) * 256
                                             + kt * 64 + k2 * 32 + quad * 8);
#pragma unroll
            for (int i = 0; i < 4; ++i)
                af[i] = *(const frag_t*)&Als[i * 16 + l15][kt * 64 + k2 * 32 + quad * 8];
#pragma unroll
            for (int i = 0; i < 4; ++i)
#pragma unroll
                for (int j = 0; j < 2; ++j)
                    acc[i][j] = __builtin_amdgcn_mfma_f32_16x16x32_bf16(af[i], bfr[j], acc[i][j], 0, 0, 0);
        }
    }

    // ---- epilogue: bias+ELU in-reg, stage 32-row halves in LDS, full-line float4 stores
    float bv[2];
#pragma unroll
    for (int j = 0; j < 2; ++j) bv[j] = bias[wv * 32 + j * 16 + l15];
#pragma unroll
    for (int p = 0; p < 2; ++p) {
        __syncthreads();     // p=0: Als frag reads done; p=1: prev pass reads done
#pragma unroll
        for (int ii = 0; ii < 2; ++ii) {
            int i = p * 2 + ii;
#pragma unroll
            for (int j = 0; j < 2; ++j) {
                int col = wv * 32 + j * 16 + l15;
#pragma unroll
                for (int r = 0; r < 4; ++r) {
                    int lr = ii * 16 + quad * 4 + r;      // local row within 32-row pass
                    float v = acc[i][j][r] + bv[j];
                    v = (v > 0.f) ? v : (__expf(v) - 1.0f);   // ELU(alpha=1), fast exp
                    Fls[lr * FLS_W + col] = v;
                }
            }
        }
        __syncthreads();
#pragma unroll
        for (int q = 0; q < 4; ++q) {                     // 32 rows x 256 cols, float4
            int f4 = q * 512 + t;
            int lr = f4 >> 6, c4 = f4 & 63;
            int grow = m0 + p * 32 + lr;
            if (grow < NN)
                *(float4*)(C + (size_t)grow * 256 + c4 * 4) = *(const float4*)&Fls[lr * FLS_W + c4 * 4];
        }
    }
}

// ---------------------------------- launcher ----------------------------------
extern "C" void kernel_launch(void* const* d_in, const int* in_sizes, int n_in,
                              void* d_out, int out_size, void* d_ws, size_t ws_size,
                              hipStream_t stream) {
    const float* x    = (const float*)d_in[0];
    const int*   nbr  = (const int*)d_in[1];
    const float* R    = (const float*)d_in[2];
    const float* Ws   = (const float*)d_in[3];
    const float* Wn   = (const float*)d_in[4];
    const float* bias = (const float*)d_in[5];
    float* out = (float*)d_out;

    // workspace layout (all 16B-aligned): ~25.7 MB
    char* ws = (char*)d_ws;
    unsigned short* xb  = (unsigned short*)(ws);              // 25,600,000 B
    unsigned short* Bbf = (unsigned short*)(ws + 25600000);   //    131,072 B

    // 3133 blocks: 0..7 = weight MFMA GEMM (8 CUs); 8..3132 = x cast (3125*512*8 = 12.8M)
    hipLaunchKernelGGL(k_prep,  dim3(3133), dim3(512), 0, stream, x, R, Ws, Wn, xb, Bbf);
    hipLaunchKernelGGL(k_fused, dim3(1563), dim3(512), 0, stream, xb, nbr, Bbf, bias, out);
}

// Round 7
// 237.097 us; speedup vs baseline: 1.3884x; 1.1374x over previous
//
#include <hip/hip_runtime.h>
#include <hip/hip_bf16.h>
#include <math.h>

// Problem constants (fixed by reference)
#define NN 100000   // nodes
#define FF 128      // features
#define DD 16       // degree
#define KK 8        // hashers
#define HH 256      // hash dim
#define OO 256      // out dim
#define KH 2048     // K*H
// C[NN,256] = A[NN,256](bf16) @ Bw[256,256](bf16), K = 2F = 256.
// A cols 0..127 = mean(neigh), 128..255 = self. Bw rows: 0..127 Wn-part, 128..255 Ws-part.
// R7 (= R6 resubmit; container failure was infra-level, same as R2->R3):
//     gather target shrunk to FP8 (OCP e4m3). R5 PMC: k_fused FETCH 188.7MB = 8 XCDs x
//     sizeof(xb) and dur = FETCH/1.81TB/s exactly -> L2-fill-BW-bound; only lever is
//     fewer fill bytes. xb8 (12.8MB) feeds the random gather; self row + MFMA stay bf16
//     (mean accumulated in f32 -> bf16). nt-hints on single-use streams (self/nbr/C).
//     k_prep weight K-loop: register-prefetch pipeline (kt+1 loads issued pre-barrier).

using frag_t  = __attribute__((ext_vector_type(8))) short;   // 8 bf16 = 4 VGPR (MFMA A/B frag)
using f32x4   = __attribute__((ext_vector_type(4))) float;   // MFMA C/D frag
using f32x2   = __attribute__((ext_vector_type(2))) float;
using ushort8 = __attribute__((ext_vector_type(8))) unsigned short;
using uv4     = __attribute__((ext_vector_type(4))) unsigned int;
using uv2     = __attribute__((ext_vector_type(2))) unsigned int;

static __device__ __forceinline__ unsigned short f2bf(float f) {
    union { float f; unsigned int i; } v; v.f = f;
    unsigned int x = v.i;
    x += 0x7fffu + ((x >> 16) & 1u);   // round-to-nearest-even
    return (unsigned short)(x >> 16);
}
static __device__ __forceinline__ unsigned int pk2(float a, float b) {
    return (unsigned int)f2bf(a) | ((unsigned int)f2bf(b) << 16);
}

// ---------------- FP8 (OCP e4m3fn) helpers: HW cvt if available, bit-exact fallback ----------------
#if defined(__has_builtin)
#if __has_builtin(__builtin_amdgcn_cvt_pk_f32_fp8) && __has_builtin(__builtin_amdgcn_cvt_pk_fp8_f32)
#define FP8_HW 1
#endif
#endif
#ifndef FP8_HW
#define FP8_HW 0
#endif

static __device__ __forceinline__ float e4m3f(unsigned int b) {   // fallback decode
    unsigned int s = (b & 0x80u) << 24;
    unsigned int em = b & 0x7fu;
    bool den = (b & 0x78u) == 0;                      // exp field == 0 -> denormal
    union { unsigned int u; float f; } v;
    v.u = s | ((em << 20) + ((den ? 121u : 120u) << 23));
    float f = v.f;
    if (den) f -= (s ? -0.015625f : 0.015625f);       // remove implicit-1 (2^-6)
    return f;
}
static __device__ __forceinline__ unsigned int f2e4m3(float f) {  // fallback encode (RNE)
    union { float f; unsigned int u; } v; v.f = f;
    unsigned int s = (v.u >> 24) & 0x80u;
    float a = fabsf(f);
    if (!(a < 448.f)) return s | 0x7Eu;               // clamp (also catches NaN)
    if (a < 0.015625f) {                              // denormal, quantum 2^-9
        int m = (int)rintf(a * 512.f);                // 0..8 (8 == e=1,m=0 bit pattern)
        return s | (unsigned int)m;
    }
    union { float f; unsigned int u; } w; w.f = a;
    unsigned int u = w.u + 0x7FFFFu + ((w.u >> 20) & 1u);   // RNE at bit 20
    return s | (((u >> 23) - 120u) << 3) | ((u >> 20) & 7u);
}
template <int SEL>   // SEL=0: bytes 0-1, SEL=1: bytes 2-3
static __device__ __forceinline__ f32x2 dec2(unsigned int w) {
#if FP8_HW
    return __builtin_amdgcn_cvt_pk_f32_fp8((int)w, SEL != 0);
#else
    f32x2 r;
    r[0] = e4m3f((w >> (SEL * 16)) & 0xffu);
    r[1] = e4m3f((w >> (SEL * 16 + 8)) & 0xffu);
    return r;
#endif
}
static __device__ __forceinline__ unsigned int enc4(float x0, float x1, float x2, float x3) {
#if FP8_HW
    int r = __builtin_amdgcn_cvt_pk_fp8_f32(x0, x1, 0, false);
    r = __builtin_amdgcn_cvt_pk_fp8_f32(x2, x3, r, true);
    return (unsigned int)r;
#else
    return f2e4m3(x0) | (f2e4m3(x1) << 8) | (f2e4m3(x2) << 16) | (f2e4m3(x3) << 24);
#endif
}

// ------- Kernel 1: prep = weight-MFMA (blocks 0..7) + x cast (blocks 8..3132) -------
// Weight block b (0..7): w=b>>2 (0=Wn,1=Ws), ot=b&3. Output Bbf[o][w*128+f] for
//   o in [ot*64,+64), f in [0,128): sum_j R[j>>8][f][j&255] * W[o][j], K=2048.
//   8 waves as 2(o)x4(f), wave tile 32x32, acc 2x2 frags 16x16x32. BK=64, 32 kt iters.
//   Register-prefetch pipeline: kt+1 global loads issued before the MFMA barrier.
// Cast blocks: 512 thr x 8 floats -> bf16 row (xb) + fp8 row (xb8).
__global__ __launch_bounds__(512) void k_prep(const float* __restrict__ x,
                                              const float* __restrict__ R,
                                              const float* __restrict__ Ws,
                                              const float* __restrict__ Wn,
                                              unsigned short* __restrict__ xb,
                                              unsigned char* __restrict__ xb8,
                                              unsigned short* __restrict__ Bbf) {
    __shared__ __align__(16) unsigned short Aw[64][72];    // W tile, bf16 ( 9.2 KB)
    __shared__ __align__(16) unsigned short Bw[128][72];   // R tile, bf16 (18.4 KB)
    int b = blockIdx.x;
    int t = threadIdx.x;
    if (b >= 8) {
        // ---- cast path ----
        int g = (b - 8) * 512 + t;
        const float4* xv = (const float4*)x;
        float4 a = xv[2 * g], c = xv[2 * g + 1];
        ushort8 o;
        o[0] = f2bf(a.x); o[1] = f2bf(a.y); o[2] = f2bf(a.z); o[3] = f2bf(a.w);
        o[4] = f2bf(c.x); o[5] = f2bf(c.y); o[6] = f2bf(c.z); o[7] = f2bf(c.w);
        *(ushort8*)(xb + (size_t)g * 8) = o;
        uv2 q;
        q.x = enc4(a.x, a.y, a.z, a.w);
        q.y = enc4(c.x, c.y, c.z, c.w);
        *(uv2*)(xb8 + (size_t)g * 8) = q;
        return;
    }
    // ---- weight MFMA path ----
    const int w = b >> 2, ot = b & 3;
    const float* W = (w == 0) ? Wn : Ws;
    int lane = t & 63, wv = t >> 6;
    int wo = wv >> 2, wf = wv & 3;            // 2(o) x 4(f) waves, 32x32 each
    int l15 = lane & 15, quad = lane >> 4;
    int rA[2], cA[2], rB[4], cB[4];
#pragma unroll
    for (int s = 0; s < 2; ++s) { int c0 = s * 512 + t; rA[s] = c0 >> 4; cA[s] = c0 & 15; }
#pragma unroll
    for (int s = 0; s < 4; ++s) { int c0 = s * 512 + t; rB[s] = c0 >> 4; cB[s] = c0 & 15; }
    float4 av[2], bv[4];
#pragma unroll
    for (int s = 0; s < 2; ++s)
        av[s] = *(const float4*)(W + (size_t)(ot * 64 + rA[s]) * KH + cA[s] * 4);
#pragma unroll
    for (int s = 0; s < 4; ++s)
        bv[s] = *(const float4*)(R + (size_t)rB[s] * 256 + cB[s] * 4);
    f32x4 acc[2][2] = {};
    for (int kt = 0; kt < 32; ++kt) {         // BK = 64
        __syncthreads();                      // prev iteration's frag reads done
#pragma unroll
        for (int s = 0; s < 2; ++s) {
            uint2 p; p.x = pk2(av[s].x, av[s].y); p.y = pk2(av[s].z, av[s].w);
            *(uint2*)&Aw[rA[s]][cA[s] * 4] = p;
        }
#pragma unroll
        for (int s = 0; s < 4; ++s) {
            uint2 p; p.x = pk2(bv[s].x, bv[s].y); p.y = pk2(bv[s].z, bv[s].w);
            *(uint2*)&Bw[rB[s]][cB[s] * 4] = p;
        }
        if (kt < 31) {                        // prefetch kt+1 (overlaps barrier+MFMA)
            int k1 = kt + 1;
#pragma unroll
            for (int s = 0; s < 2; ++s)
                av[s] = *(const float4*)(W + (size_t)(ot * 64 + rA[s]) * KH + k1 * 64 + cA[s] * 4);
#pragma unroll
            for (int s = 0; s < 4; ++s)
                bv[s] = *(const float4*)(R + (size_t)(k1 >> 2) * 32768
                                           + (size_t)rB[s] * 256 + (k1 & 3) * 64 + cB[s] * 4);
        }
        __syncthreads();
#pragma unroll
        for (int k2 = 0; k2 < 2; ++k2) {
            frag_t af[2], bfr[2];
#pragma unroll
            for (int i = 0; i < 2; ++i)
                af[i] = *(const frag_t*)&Aw[wo * 32 + i * 16 + l15][k2 * 32 + quad * 8];
#pragma unroll
            for (int j = 0; j < 2; ++j)
                bfr[j] = *(const frag_t*)&Bw[wf * 32 + j * 16 + l15][k2 * 32 + quad * 8];
#pragma unroll
            for (int i = 0; i < 2; ++i)
#pragma unroll
                for (int j = 0; j < 2; ++j)
                    acc[i][j] = __builtin_amdgcn_mfma_f32_16x16x32_bf16(af[i], bfr[j], acc[i][j], 0, 0, 0);
        }
    }
    // write Bbf[o][w*128+f]; C/D layout: col(n)=l15 -> f (R-row), row(m)=quad*4+r -> o (W-row)
#pragma unroll
    for (int j = 0; j < 2; ++j) {
        int f = wf * 32 + j * 16 + l15;
#pragma unroll
        for (int i = 0; i < 2; ++i) {
            int o0 = ot * 64 + wo * 32 + i * 16 + quad * 4;
#pragma unroll
            for (int r = 0; r < 4; ++r)
                Bbf[(size_t)(o0 + r) * 256 + w * 128 + f] = f2bf(acc[i][j][r]);
        }
    }
}

// --------- Kernel 2 (fused): fp8 gather-mean -> LDS A-tile -> MFMA GEMM + bias + ELU ---------
// BM=64 x BN=256, 512 threads = 8 waves, wave tile 64x32 (acc 4x2 frags).
// Gather reads xb8 (fp8, 12.8 MB): lane=(r4,l16), one dwordx2 = 4 rows x 8B; nbr idx
//   broadcast per-d via ds_bpermute; 2 batches of 8 loads in flight. Mean in f32 -> bf16.
// Self row from xb (bf16) via nt-load (single-use stream; keep L2 for xb8).
// LDS: Als[64][264] bf16 only (33.8 KB); B-frags straight from global (128 KB, L2-hot);
//   K-loop barrier-free. Epilogue: LDS-staged full-line nt float4 stores.
__global__ __launch_bounds__(512, 4) void k_fused(const unsigned short* __restrict__ xb,
                                                  const unsigned char* __restrict__ xb8,
                                                  const int* __restrict__ nbr,
                                                  const unsigned short* __restrict__ Bw,
                                                  const float* __restrict__ bias,
                                                  float* __restrict__ C) {
    __shared__ __align__(16) char smraw[64 * 264 * 2];   // 33792 B, dual-purpose
    unsigned short (*Als)[264] = (unsigned short (*)[264])smraw;
    float* Fls = (float*)smraw;                          // [32][260] floats (33280 B)
    const int FLS_W = 260;

    int m0 = blockIdx.x * 64;
    int t = threadIdx.x;
    int lane = t & 63, wv = t >> 6;           // 8 waves
    int l15 = lane & 15, quad = lane >> 4;
    int l16 = lane & 15, r4 = lane >> 4;      // gather mapping: 4 rows x 16 feature-lanes
    int selbase = (lane & 48) << 2;           // bpermute selector base (group start lane *4)

    // ---- gather phase: 2 groups of 4 rows; per group 2 batches of 8 dwordx2 in flight
#pragma unroll
    for (int g = 0; g < 2; ++g) {
        int row = wv * 8 + g * 4 + r4;                    // block-local row 0..63
        int node = m0 + row; if (node >= NN) node = NN - 1;
        int myidx = __builtin_nontemporal_load(nbr + (size_t)node * 16 + l16);
        uv4 selfv = __builtin_nontemporal_load(
            (const uv4*)(xb + (size_t)node * 128 + l16 * 8));
        float s[8] = {0.f, 0.f, 0.f, 0.f, 0.f, 0.f, 0.f, 0.f};
#pragma unroll
        for (int h = 0; h < 2; ++h) {                     // 2 batches of 8 loads in flight
            uv2 gv[8];
#pragma unroll
            for (int d = 0; d < 8; ++d) {
                int bi = __builtin_amdgcn_ds_bpermute(selbase + ((h * 8 + d) << 2), myidx);
                gv[d] = *(const uv2*)(xb8 + (size_t)bi * 128 + l16 * 8);
            }
#pragma unroll
            for (int d = 0; d < 8; ++d) {
                f32x2 p;
                p = dec2<0>(gv[d].x); s[0] += p[0]; s[1] += p[1];
                p = dec2<1>(gv[d].x); s[2] += p[0]; s[3] += p[1];
                p = dec2<0>(gv[d].y); s[4] += p[0]; s[5] += p[1];
                p = dec2<1>(gv[d].y); s[6] += p[0]; s[7] += p[1];
            }
        }
        ushort8 o;
#pragma unroll
        for (int k = 0; k < 8; ++k) o[k] = f2bf(s[k] * 0.0625f);
        *(ushort8*)&Als[row][l16 * 8] = o;                // mean features 0..127
        *(uv4*)&Als[row][128 + l16 * 8] = selfv;          // self features 128..255
    }
    __syncthreads();

    // ---- K-loop: barrier-free; B-frags from global (L2-hot 128 KB)
    f32x4 acc[4][2] = {};
#pragma unroll 1
    for (int kt = 0; kt < 4; ++kt) {
#pragma unroll
        for (int k2 = 0; k2 < 2; ++k2) {
            frag_t bfr[2], af[4];
#pragma unroll
            for (int j = 0; j < 2; ++j)
                bfr[j] = *(const frag_t*)(Bw + (size_t)(wv * 32 + j * 16 + l15) * 256
                                             + kt * 64 + k2 * 32 + quad * 8);
#pragma unroll
            for (int i = 0; i < 4; ++i)
                af[i] = *(const frag_t*)&Als[i * 16 + l15][kt * 64 + k2 * 32 + quad * 8];
#pragma unroll
            for (int i = 0; i < 4; ++i)
#pragma unroll
                for (int j = 0; j < 2; ++j)
                    acc[i][j] = __builtin_amdgcn_mfma_f32_16x16x32_bf16(af[i], bfr[j], acc[i][j], 0, 0, 0);
        }
    }

    // ---- epilogue: bias+ELU in-reg, stage 32-row halves in LDS, full-line nt stores
    float bv[2];
#pragma unroll
    for (int j = 0; j < 2; ++j) bv[j] = bias[wv * 32 + j * 16 + l15];
#pragma unroll
    for (int p = 0; p < 2; ++p) {
        __syncthreads();     // p=0: Als frag reads done; p=1: prev pass reads done
#pragma unroll
        for (int ii = 0; ii < 2; ++ii) {
            int i = p * 2 + ii;
#pragma unroll
            for (int j = 0; j < 2; ++j) {
                int col = wv * 32 + j * 16 + l15;
#pragma unroll
                for (int r = 0; r < 4; ++r) {
                    int lr = ii * 16 + quad * 4 + r;      // local row within 32-row pass
                    float v = acc[i][j][r] + bv[j];
                    v = (v > 0.f) ? v : (__expf(v) - 1.0f);   // ELU(alpha=1), fast exp
                    Fls[lr * FLS_W + col] = v;
                }
            }
        }
        __syncthreads();
#pragma unroll
        for (int q = 0; q < 4; ++q) {                     // 32 rows x 256 cols, float4
            int f4 = q * 512 + t;
            int lr = f4 >> 6, c4 = f4 & 63;
            int grow = m0 + p * 32 + lr;
            if (grow < NN)
                __builtin_nontemporal_store(*(const f32x4*)&Fls[lr * FLS_W + c4 * 4],
                                            (f32x4*)(C + (size_t)grow * 256 + c4 * 4));
        }
    }
}

// ---------------------------------- launcher ----------------------------------
extern "C" void kernel_launch(void* const* d_in, const int* in_sizes, int n_in,
                              void* d_out, int out_size, void* d_ws, size_t ws_size,
                              hipStream_t stream) {
    const float* x    = (const float*)d_in[0];
    const int*   nbr  = (const int*)d_in[1];
    const float* R    = (const float*)d_in[2];
    const float* Ws   = (const float*)d_in[3];
    const float* Wn   = (const float*)d_in[4];
    const float* bias = (const float*)d_in[5];
    float* out = (float*)d_out;

    // workspace layout (all 16B-aligned): ~38.5 MB
    char* ws = (char*)d_ws;
    unsigned short* xb  = (unsigned short*)(ws);              // 25,600,000 B (bf16, self)
    unsigned char*  xb8 = (unsigned char*)(ws + 25600000);    // 12,800,000 B (fp8, gather)
    unsigned short* Bbf = (unsigned short*)(ws + 38400000);   //    131,072 B

    // 3133 blocks: 0..7 = weight MFMA GEMM (8 CUs); 8..3132 = x cast (3125*512*8 = 12.8M)
    hipLaunchKernelGGL(k_prep,  dim3(3133), dim3(512), 0, stream, x, R, Ws, Wn, xb, xb8, Bbf);
    hipLaunchKernelGGL(k_fused, dim3(1563), dim3(512), 0, stream, xb, xb8, nbr, Bbf, bias, out);
}